// Round 3
// baseline (461.136 us; speedup 1.0000x reference)
//
#include <hip/hip_runtime.h>

#define LL 4096
#define HH 1024
#define PP 512
#define RR 16
#define CH 128   // scan chunks
#define CL 32    // steps per chunk

typedef _Float16 f16x8 __attribute__((ext_vector_type(8)));
typedef float f32x4 __attribute__((ext_vector_type(4)));
typedef unsigned short u16;

#define MF16(a, b, c) __builtin_amdgcn_mfma_f32_16x16x32_f16(a, b, c, 0, 0, 0)

__device__ __forceinline__ void splitf(float x, u16& h, u16& l) {
  _Float16 hf = (_Float16)x;
  _Float16 lf = (_Float16)(x - (float)hf);
  h = __builtin_bit_cast(u16, hf);
  l = __builtin_bit_cast(u16, lf);
}

// ---------------------------------------------------------------- precompute
__global__ void precompute_kernel(const float* __restrict__ Lre, const float* __restrict__ Lim,
                                  const float* __restrict__ lst,
                                  const float* __restrict__ Ere, const float* __restrict__ Eim,
                                  const float* __restrict__ Fre, const float* __restrict__ Fim,
                                  float* __restrict__ Lbr, float* __restrict__ Lbi,
                                  float* __restrict__ cfr, float* __restrict__ cfi,
                                  float* __restrict__ EFr, float* __restrict__ EFi)
{
  int p = blockIdx.x * blockDim.x + threadIdx.x;
  if (p >= PP) return;
  float lre = fminf(Lre[p], -1e-4f);   // clip_eigs
  float lim = Lim[p];
  float st  = expf(lst[p]);
  float er  = expf(lre * st);
  float s, c;
  sincosf(lim * st, &s, &c);
  float lbr = er * c, lbi = er * s;    // Lambda_bar
  Lbr[p] = lbr; Lbi[p] = lbi;
  float den = lre * lre + lim * lim;
  float nr  = lbr - 1.0f;
  cfr[p] = (nr * lre + lbi * lim) / den;
  cfi[p] = (lbi * lre - nr * lim) / den;
  for (int r = 0; r < RR; ++r) {
    float e_r = Ere[p * RR + r], e_i = Eim[p * RR + r];
    float f_r = Fre[r * PP + p], f_i = Fim[r * PP + p];
    EFr[r * PP + p] = e_r * f_r - e_i * f_i;
    EFi[r * PP + p] = e_r * f_i + e_i * f_r;
  }
}

// ---------------------------------------------------------------- B_bar -> fp16 hi/lo planes
__global__ void bbar_kernel(const float* __restrict__ Bre, const float* __restrict__ Bim,
                            const float* __restrict__ cfr, const float* __restrict__ cfi,
                            u16* __restrict__ brh, u16* __restrict__ brl,
                            u16* __restrict__ bih, u16* __restrict__ bil)
{
  int i = blockIdx.x * blockDim.x + threadIdx.x;
  int base = i * 4;
  if (base >= PP * HH) return;
  int p = base >> 10;
  float cr = cfr[p], ci = cfi[p];
  float4 br = *(const float4*)&Bre[base];
  float4 bi = *(const float4*)&Bim[base];
  ushort4 rh, rl, ih, il;
  float re, im;
  re = cr*br.x - ci*bi.x; im = cr*bi.x + ci*br.x; splitf(re, rh.x, rl.x); splitf(im, ih.x, il.x);
  re = cr*br.y - ci*bi.y; im = cr*bi.y + ci*br.y; splitf(re, rh.y, rl.y); splitf(im, ih.y, il.y);
  re = cr*br.z - ci*bi.z; im = cr*bi.z + ci*br.z; splitf(re, rh.z, rl.z); splitf(im, ih.z, il.z);
  re = cr*br.w - ci*bi.w; im = cr*bi.w + ci*br.w; splitf(re, rh.w, rl.w); splitf(im, ih.w, il.w);
  *(ushort4*)&brh[base] = rh;
  *(ushort4*)&brl[base] = rl;
  *(ushort4*)&bih[base] = ih;
  *(ushort4*)&bil[base] = il;
}

// ---------------------------------------------------------------- u -> fp16 hi/lo
__global__ void split_u_kernel(const float* __restrict__ U,
                               u16* __restrict__ uh, u16* __restrict__ ul)
{
  int i = blockIdx.x * blockDim.x + threadIdx.x;
  int base = i * 4;
  float4 v = *(const float4*)&U[base];
  ushort4 h, l;
  splitf(v.x, h.x, l.x); splitf(v.y, h.y, l.y);
  splitf(v.z, h.z, l.z); splitf(v.w, h.w, l.w);
  *(ushort4*)&uh[base] = h;
  *(ushort4*)&ul[base] = l;
}

// ---------------------------------------------------------------- C -> fp16 hi/lo (Cim negated)
__global__ void convc_kernel(const float* __restrict__ Cre, const float* __restrict__ Cim,
                             u16* __restrict__ crh, u16* __restrict__ crl,
                             u16* __restrict__ cih, u16* __restrict__ cil)
{
  int i = blockIdx.x * blockDim.x + threadIdx.x;
  int base = i * 4;
  float4 a = *(const float4*)&Cre[base];
  float4 b = *(const float4*)&Cim[base];
  ushort4 rh, rl, ih, il;
  splitf(a.x, rh.x, rl.x); splitf(-b.x, ih.x, il.x);
  splitf(a.y, rh.y, rl.y); splitf(-b.y, ih.y, il.y);
  splitf(a.z, rh.z, rl.z); splitf(-b.z, ih.z, il.z);
  splitf(a.w, rh.w, rl.w); splitf(-b.w, ih.w, il.w);
  *(ushort4*)&crh[base] = rh;
  *(ushort4*)&crl[base] = rl;
  *(ushort4*)&cih[base] = ih;
  *(ushort4*)&cil[base] = il;
}

// ---------------------------------------------------------------- Lambda elements (fp32)
__global__ __launch_bounds__(256) void lambda_kernel(
    const float* __restrict__ Dt, const float* __restrict__ EFr, const float* __restrict__ EFi,
    const float* __restrict__ Lbr, const float* __restrict__ Lbi,
    float* __restrict__ Ler, float* __restrict__ Lei)
{
  int gid = blockIdx.x * 256 + threadIdx.x;
  int l  = gid >> 7;
  int pq = (gid & 127) << 2;
  float4 ar = *(const float4*)&Lbr[pq];
  float4 ai = *(const float4*)&Lbi[pq];
#pragma unroll
  for (int r = 0; r < RR; ++r) {
    float d = Dt[l * RR + r];
    float4 er = *(const float4*)&EFr[r * PP + pq];
    float4 ei = *(const float4*)&EFi[r * PP + pq];
    ar.x = fmaf(d, er.x, ar.x); ar.y = fmaf(d, er.y, ar.y);
    ar.z = fmaf(d, er.z, ar.z); ar.w = fmaf(d, er.w, ar.w);
    ai.x = fmaf(d, ei.x, ai.x); ai.y = fmaf(d, ei.y, ai.y);
    ai.z = fmaf(d, ei.z, ai.z); ai.w = fmaf(d, ei.w, ai.w);
  }
  *(float4*)&Ler[(size_t)l * PP + pq] = ar;
  *(float4*)&Lei[(size_t)l * PP + pq] = ai;
}

// ---------------------------------------------------------------- gemm1: Bu = u @ B_bar^T (split-f16 MFMA)
// block tile 64(L) x 64(P), 4 waves 2x2, wave tile 32x32
__global__ __launch_bounds__(256, 2) void gemm1_mfma(
    const u16* __restrict__ uh, const u16* __restrict__ ul,
    const u16* __restrict__ brh, const u16* __restrict__ brl,
    const u16* __restrict__ bih, const u16* __restrict__ bil,
    float* __restrict__ Bur, float* __restrict__ Bui)
{
  __shared__ u16 lds[64 * 72 + 64 * 136];   // A: 2 planes/row (72 shorts), B: 4 planes/row (136)
  const int BOFF = 64 * 72;
  int t = threadIdx.x;
  int p0 = blockIdx.x * 64, l0 = blockIdx.y * 64;
  int w = t >> 6, lane = t & 63;
  int wr = w >> 1, wc = w & 1;
  int rl = lane & 15, kg = lane >> 4;

  const u16* gA = ((t >> 2) & 1) ? ul : uh;
  const u16* Bp4[4] = {brh, brl, bih, bil};
  const u16* gB = Bp4[(t >> 2) & 3];
  int cg  = t & 3;
  int arw = (t >> 3) & 31;   // A rows arw, arw+32
  int brw = t >> 4;          // B rows brw + 16*i
  int pa = (t >> 2) & 1, pb = (t >> 2) & 3;
  uint4 sA[2], sB[4];

  f32x4 accr[2][2], acci[2][2];
#pragma unroll
  for (int m = 0; m < 2; ++m)
#pragma unroll
    for (int n = 0; n < 2; ++n) {
      accr[m][n] = (f32x4){0.f, 0.f, 0.f, 0.f};
      acci[m][n] = (f32x4){0.f, 0.f, 0.f, 0.f};
    }

#define G1_LOADT(kt) do {                                                     \
    int kc = (kt) * 32 + cg * 8;                                              \
    sA[0] = *(const uint4*)&gA[(size_t)(l0 + arw)      * HH + kc];            \
    sA[1] = *(const uint4*)&gA[(size_t)(l0 + arw + 32) * HH + kc];            \
    sB[0] = *(const uint4*)&gB[(size_t)(p0 + brw)      * HH + kc];            \
    sB[1] = *(const uint4*)&gB[(size_t)(p0 + brw + 16) * HH + kc];            \
    sB[2] = *(const uint4*)&gB[(size_t)(p0 + brw + 32) * HH + kc];            \
    sB[3] = *(const uint4*)&gB[(size_t)(p0 + brw + 48) * HH + kc];            \
  } while (0)
#define G1_WRITET() do {                                                      \
    *(uint4*)&lds[(arw)      * 72 + pa * 32 + cg * 8] = sA[0];                \
    *(uint4*)&lds[(arw + 32) * 72 + pa * 32 + cg * 8] = sA[1];                \
    *(uint4*)&lds[BOFF + (brw)      * 136 + pb * 32 + cg * 8] = sB[0];        \
    *(uint4*)&lds[BOFF + (brw + 16) * 136 + pb * 32 + cg * 8] = sB[1];        \
    *(uint4*)&lds[BOFF + (brw + 32) * 136 + pb * 32 + cg * 8] = sB[2];        \
    *(uint4*)&lds[BOFF + (brw + 48) * 136 + pb * 32 + cg * 8] = sB[3];        \
  } while (0)

  G1_LOADT(0); G1_WRITET(); __syncthreads();
  for (int kt = 0; kt < HH / 32; ++kt) {
    if (kt + 1 < HH / 32) G1_LOADT(kt + 1);
    f16x8 fb[2][4];
#pragma unroll
    for (int nf = 0; nf < 2; ++nf) {
      int rowB = BOFF + (wc * 32 + nf * 16 + rl) * 136 + kg * 8;
#pragma unroll
      for (int pl = 0; pl < 4; ++pl)
        fb[nf][pl] = *(const f16x8*)&lds[rowB + pl * 32];
    }
#pragma unroll
    for (int mf = 0; mf < 2; ++mf) {
      int rowA = (wr * 32 + mf * 16 + rl) * 72 + kg * 8;
      f16x8 fh = *(const f16x8*)&lds[rowA];
      f16x8 fl = *(const f16x8*)&lds[rowA + 32];
#pragma unroll
      for (int nf = 0; nf < 2; ++nf) {
        accr[mf][nf] = MF16(fh, fb[nf][0], accr[mf][nf]);
        accr[mf][nf] = MF16(fh, fb[nf][1], accr[mf][nf]);
        accr[mf][nf] = MF16(fl, fb[nf][0], accr[mf][nf]);
        acci[mf][nf] = MF16(fh, fb[nf][2], acci[mf][nf]);
        acci[mf][nf] = MF16(fh, fb[nf][3], acci[mf][nf]);
        acci[mf][nf] = MF16(fl, fb[nf][2], acci[mf][nf]);
      }
    }
    __syncthreads();
    if (kt + 1 < HH / 32) G1_WRITET();
    __syncthreads();
  }
#pragma unroll
  for (int nf = 0; nf < 2; ++nf) {
    int c = p0 + wc * 32 + nf * 16 + rl;
#pragma unroll
    for (int mf = 0; mf < 2; ++mf) {
      int r0 = l0 + wr * 32 + mf * 16 + kg * 4;
#pragma unroll
      for (int j = 0; j < 4; ++j) {
        Bur[(size_t)(r0 + j) * PP + c] = accr[mf][nf][j];
        Bui[(size_t)(r0 + j) * PP + c] = acci[mf][nf][j];
      }
    }
  }
}

// ---------------------------------------------------------------- scan phase 1
__global__ __launch_bounds__(256) void scan_agg_kernel(
    const float* __restrict__ Aer, const float* __restrict__ Aei,
    const float* __restrict__ Bur, const float* __restrict__ Bui,
    float* __restrict__ aggAr, float* __restrict__ aggAi,
    float* __restrict__ aggBr, float* __restrict__ aggBi)
{
  int tid = blockIdx.x * 256 + threadIdx.x;
  int p   = tid & (PP - 1);
  int c   = (tid >> 9) & (CH - 1);
  int dir = tid >> 16;
  float Ar = 1.f, Ai = 0.f, br = 0.f, bi = 0.f;
  int base = c * CL;
#pragma unroll
  for (int g = 0; g < CL / 8; ++g) {
    float ar8[8], ai8[8], br8[8], bi8[8];
#pragma unroll
    for (int u = 0; u < 8; ++u) {
      int l = base + g * 8 + u;
      int phys = dir ? (LL - 1 - l) : l;
      int idx = phys * PP + p;
      ar8[u] = Aer[idx]; ai8[u] = Aei[idx];
      br8[u] = Bur[idx]; bi8[u] = Bui[idx];
    }
#pragma unroll
    for (int u = 0; u < 8; ++u) {
      float nAr = ar8[u] * Ar - ai8[u] * Ai;
      float nAi = ar8[u] * Ai + ai8[u] * Ar;
      float nbr = fmaf(ar8[u], br, fmaf(-ai8[u], bi, br8[u]));
      float nbi = fmaf(ar8[u], bi, fmaf( ai8[u], br, bi8[u]));
      Ar = nAr; Ai = nAi; br = nbr; bi = nbi;
    }
  }
  aggAr[tid] = Ar; aggAi[tid] = Ai; aggBr[tid] = br; aggBi[tid] = bi;
}

// ---------------------------------------------------------------- scan phase 2
__global__ __launch_bounds__(256) void scan_carry_kernel(
    const float* __restrict__ aggAr, const float* __restrict__ aggAi,
    const float* __restrict__ aggBr, const float* __restrict__ aggBi,
    float* __restrict__ carR, float* __restrict__ carI)
{
  int tid = blockIdx.x * 256 + threadIdx.x;
  int p   = tid & (PP - 1);
  int dir = tid >> 9;
  float xr = 0.f, xi = 0.f;
  for (int c = 0; c < CH; ++c) {
    int idx = (dir * CH + c) * PP + p;
    carR[idx] = xr; carI[idx] = xi;
    float ar = aggAr[idx], ai = aggAi[idx];
    float br = aggBr[idx], bi = aggBi[idx];
    float nr = fmaf(ar, xr, fmaf(-ai, xi, br));
    float ni = fmaf(ar, xi, fmaf( ai, xr, bi));
    xr = nr; xi = ni;
  }
}

// ---------------------------------------------------------------- scan phase 3 (writes fp16 hi/lo planes)
__global__ __launch_bounds__(256) void scan_apply_kernel(
    const float* __restrict__ Aer, const float* __restrict__ Aei,
    const float* __restrict__ Bur, const float* __restrict__ Bui,
    const float* __restrict__ carR, const float* __restrict__ carI,
    u16* __restrict__ xrh, u16* __restrict__ xrl,
    u16* __restrict__ xih, u16* __restrict__ xil)
{
  int tid = blockIdx.x * 256 + threadIdx.x;
  int p   = tid & (PP - 1);
  int c   = (tid >> 9) & (CH - 1);
  int dir = tid >> 16;
  float xr = carR[tid], xi = carI[tid];
  int base = c * CL;
  int cofs = dir * PP + p;      // column in merged [L][2P] planes
#pragma unroll
  for (int g = 0; g < CL / 8; ++g) {
    float ar8[8], ai8[8], br8[8], bi8[8];
#pragma unroll
    for (int u = 0; u < 8; ++u) {
      int l = base + g * 8 + u;
      int phys = dir ? (LL - 1 - l) : l;
      int idx = phys * PP + p;
      ar8[u] = Aer[idx]; ai8[u] = Aei[idx];
      br8[u] = Bur[idx]; bi8[u] = Bui[idx];
    }
#pragma unroll
    for (int u = 0; u < 8; ++u) {
      float nr = fmaf(ar8[u], xr, fmaf(-ai8[u], xi, br8[u]));
      float ni = fmaf(ar8[u], xi, fmaf( ai8[u], xr, bi8[u]));
      xr = nr; xi = ni;
      int l = base + g * 8 + u;
      int phys = dir ? (LL - 1 - l) : l;
      size_t col = (size_t)phys * (2 * PP) + cofs;
      u16 h, lo;
      splitf(xr, h, lo); xrh[col] = h; xrl[col] = lo;
      splitf(xi, h, lo); xih[col] = h; xil[col] = lo;
    }
  }
}

// ---------------------------------------------------------------- gemm2: Y = 2*Re(xs @ C^T) + D*u (split-f16 MFMA)
// block tile 128(L) x 64(H), 4 waves 2x2, wave tile 64x32
__global__ __launch_bounds__(256, 2) void gemm2_mfma(
    const u16* __restrict__ xrh, const u16* __restrict__ xrl,
    const u16* __restrict__ xih, const u16* __restrict__ xil,
    const u16* __restrict__ crh, const u16* __restrict__ crl,
    const u16* __restrict__ cih, const u16* __restrict__ cil,
    const float* __restrict__ Dv, const float* __restrict__ U,
    float* __restrict__ Y)
{
  __shared__ u16 lds[128 * 136 + 64 * 136];  // A: 4 planes/row, B: 4 planes/row
  const int BOFF = 128 * 136;
  int t = threadIdx.x;
  int h0 = blockIdx.x * 64, l0 = blockIdx.y * 128;
  int w = t >> 6, lane = t & 63;
  int wr = w >> 1, wc = w & 1;
  int rl = lane & 15, kg = lane >> 4;

  const u16* Ap4[4] = {xrh, xrl, xih, xil};
  const u16* Bp4[4] = {crh, crl, cih, cil};
  const u16* gA = Ap4[(t >> 2) & 3];
  const u16* gB = Bp4[(t >> 2) & 3];
  int cg = t & 3;
  int rw = t >> 4;               // A rows rw+16i (i<8), B rows rw+16i (i<4)
  int pl4 = (t >> 2) & 3;
  uint4 sA[8], sB[4];

  f32x4 acc[4][2];
#pragma unroll
  for (int m = 0; m < 4; ++m)
#pragma unroll
    for (int n = 0; n < 2; ++n) acc[m][n] = (f32x4){0.f, 0.f, 0.f, 0.f};

#define G2_LOADT(kt) do {                                                     \
    int kc = (kt) * 32 + cg * 8;                                              \
    _Pragma("unroll")                                                         \
    for (int i2 = 0; i2 < 8; ++i2)                                            \
      sA[i2] = *(const uint4*)&gA[(size_t)(l0 + rw + 16 * i2) * HH + kc];     \
    _Pragma("unroll")                                                         \
    for (int i2 = 0; i2 < 4; ++i2)                                            \
      sB[i2] = *(const uint4*)&gB[(size_t)(h0 + rw + 16 * i2) * HH + kc];     \
  } while (0)
#define G2_WRITET() do {                                                      \
    _Pragma("unroll")                                                         \
    for (int i2 = 0; i2 < 8; ++i2)                                            \
      *(uint4*)&lds[(rw + 16 * i2) * 136 + pl4 * 32 + cg * 8] = sA[i2];       \
    _Pragma("unroll")                                                         \
    for (int i2 = 0; i2 < 4; ++i2)                                            \
      *(uint4*)&lds[BOFF + (rw + 16 * i2) * 136 + pl4 * 32 + cg * 8] = sB[i2];\
  } while (0)

  G2_LOADT(0); G2_WRITET(); __syncthreads();
  for (int kt = 0; kt < HH / 32; ++kt) {
    if (kt + 1 < HH / 32) G2_LOADT(kt + 1);
    f16x8 fb[2][4];
#pragma unroll
    for (int nf = 0; nf < 2; ++nf) {
      int rowB = BOFF + (wc * 32 + nf * 16 + rl) * 136 + kg * 8;
#pragma unroll
      for (int pl = 0; pl < 4; ++pl)
        fb[nf][pl] = *(const f16x8*)&lds[rowB + pl * 32];
    }
#pragma unroll
    for (int mf = 0; mf < 4; ++mf) {
      int rowA = (wr * 64 + mf * 16 + rl) * 136 + kg * 8;
      f16x8 arh = *(const f16x8*)&lds[rowA];
      f16x8 arl = *(const f16x8*)&lds[rowA + 32];
      f16x8 aih = *(const f16x8*)&lds[rowA + 64];
      f16x8 ail = *(const f16x8*)&lds[rowA + 96];
#pragma unroll
      for (int nf = 0; nf < 2; ++nf) {
        acc[mf][nf] = MF16(arh, fb[nf][0], acc[mf][nf]);
        acc[mf][nf] = MF16(arh, fb[nf][1], acc[mf][nf]);
        acc[mf][nf] = MF16(arl, fb[nf][0], acc[mf][nf]);
        acc[mf][nf] = MF16(aih, fb[nf][2], acc[mf][nf]);
        acc[mf][nf] = MF16(aih, fb[nf][3], acc[mf][nf]);
        acc[mf][nf] = MF16(ail, fb[nf][2], acc[mf][nf]);
      }
    }
    __syncthreads();
    if (kt + 1 < HH / 32) G2_WRITET();
    __syncthreads();
  }
#pragma unroll
  for (int nf = 0; nf < 2; ++nf) {
    int c = h0 + wc * 32 + nf * 16 + rl;
    float dv = Dv[c];
#pragma unroll
    for (int mf = 0; mf < 4; ++mf) {
      int r0 = l0 + wr * 64 + mf * 16 + kg * 4;
#pragma unroll
      for (int j = 0; j < 4; ++j) {
        size_t idx = (size_t)(r0 + j) * HH + c;
        Y[idx] = 2.0f * acc[mf][nf][j] + dv * U[idx];
      }
    }
  }
}

// ---------------------------------------------------------------- launch
extern "C" void kernel_launch(void* const* d_in, const int* in_sizes, int n_in,
                              void* d_out, int out_size, void* d_ws, size_t ws_size,
                              hipStream_t stream)
{
  const float* U   = (const float*)d_in[0];
  const float* Lre = (const float*)d_in[1];
  const float* Lim = (const float*)d_in[2];
  const float* Bre = (const float*)d_in[3];
  const float* Bim = (const float*)d_in[4];
  const float* Cre = (const float*)d_in[5];
  const float* Cim = (const float*)d_in[6];
  const float* Ere = (const float*)d_in[7];
  const float* Eim = (const float*)d_in[8];
  const float* Fre = (const float*)d_in[9];
  const float* Fim = (const float*)d_in[10];
  const float* Dv  = (const float*)d_in[11];
  const float* lst = (const float*)d_in[12];
  const float* Dt  = (const float*)d_in[13];
  float* Y = (float*)d_out;

  char* wsb = (char*)d_ws;
  size_t o = 0;
  auto alloc = [&](size_t bytes) -> char* {
    char* r = wsb + o; o += (bytes + 255) & ~(size_t)255; return r;
  };
  float* Lbr = (float*)alloc(PP * 4);
  float* Lbi = (float*)alloc(PP * 4);
  float* cfr = (float*)alloc(PP * 4);
  float* cfi = (float*)alloc(PP * 4);
  float* EFr = (float*)alloc((size_t)RR * PP * 4);
  float* EFi = (float*)alloc((size_t)RR * PP * 4);
  u16* uh  = (u16*)alloc((size_t)LL * HH * 2);
  u16* ul  = (u16*)alloc((size_t)LL * HH * 2);
  u16* brh = (u16*)alloc((size_t)PP * HH * 2);
  u16* brl = (u16*)alloc((size_t)PP * HH * 2);
  u16* bih = (u16*)alloc((size_t)PP * HH * 2);
  u16* bil = (u16*)alloc((size_t)PP * HH * 2);
  float* Ler = (float*)alloc((size_t)LL * PP * 4);
  float* Lei = (float*)alloc((size_t)LL * PP * 4);
  float* Bur = (float*)alloc((size_t)LL * PP * 4);
  float* Bui = (float*)alloc((size_t)LL * PP * 4);
  u16* xrh = (u16*)alloc((size_t)LL * 2 * PP * 2);
  u16* xrl = (u16*)alloc((size_t)LL * 2 * PP * 2);
  u16* xih = (u16*)alloc((size_t)LL * 2 * PP * 2);
  u16* xil = (u16*)alloc((size_t)LL * 2 * PP * 2);

  // overlays: C planes on uh/ul (dead after gemm1); scan agg/carry on B_bar planes
  u16* crh = uh;
  u16* crl = crh + (size_t)HH * HH;
  u16* cih = crl + (size_t)HH * HH;
  u16* cil = cih + (size_t)HH * HH;   // 8 MB total inside uh+ul (16 MB)
  const int NAGG = 2 * CH * PP;       // 131072
  float* aggAr = (float*)brh;
  float* aggAi = aggAr + NAGG;
  float* aggBr = aggAr + 2 * (size_t)NAGG;
  float* aggBi = aggAr + 3 * (size_t)NAGG;
  float* carR  = aggAr + 4 * (size_t)NAGG;
  float* carI  = aggAr + 5 * (size_t)NAGG;  // 3 MB inside 4 MB B_bar region

  precompute_kernel<<<2, 256, 0, stream>>>(Lre, Lim, lst, Ere, Eim, Fre, Fim,
                                           Lbr, Lbi, cfr, cfi, EFr, EFi);
  bbar_kernel<<<PP * HH / 4 / 256, 256, 0, stream>>>(Bre, Bim, cfr, cfi, brh, brl, bih, bil);
  split_u_kernel<<<LL * HH / 4 / 256, 256, 0, stream>>>(U, uh, ul);
  lambda_kernel<<<LL * PP / 4 / 256, 256, 0, stream>>>(Dt, EFr, EFi, Lbr, Lbi, Ler, Lei);
  gemm1_mfma<<<dim3(PP / 64, LL / 64), 256, 0, stream>>>(uh, ul, brh, brl, bih, bil, Bur, Bui);
  scan_agg_kernel<<<2 * CH * PP / 256, 256, 0, stream>>>(Ler, Lei, Bur, Bui,
                                                         aggAr, aggAi, aggBr, aggBi);
  scan_carry_kernel<<<4, 256, 0, stream>>>(aggAr, aggAi, aggBr, aggBi, carR, carI);
  scan_apply_kernel<<<2 * CH * PP / 256, 256, 0, stream>>>(Ler, Lei, Bur, Bui, carR, carI,
                                                           xrh, xrl, xih, xil);
  convc_kernel<<<HH * 2 * PP / 4 / 256, 256, 0, stream>>>(Cre, Cim, crh, crl, cih, cil);
  gemm2_mfma<<<dim3(HH / 64, LL / 128), 256, 0, stream>>>(xrh, xrl, xih, xil,
                                                          crh, crl, cih, cil, Dv, U, Y);
}

// Round 4
// 237.511 us; speedup vs baseline: 1.9415x; 1.9415x over previous
//
#include <hip/hip_runtime.h>

#define LL 4096
#define HH 1024
#define PP 512
#define RR 16
#define CH 128   // scan chunks
#define CL 32    // steps per chunk

typedef _Float16 f16x8 __attribute__((ext_vector_type(8)));
typedef float f32x4 __attribute__((ext_vector_type(4)));
typedef unsigned short u16;

#define MF16(a, b, c) __builtin_amdgcn_mfma_f32_16x16x32_f16(a, b, c, 0, 0, 0)

__device__ __forceinline__ u16 h16(float x) {
  _Float16 h = (_Float16)x;
  return __builtin_bit_cast(u16, h);
}
__device__ __forceinline__ void splitf(float x, u16& h, u16& l) {
  _Float16 hf = (_Float16)x;
  _Float16 lf = (_Float16)(x - (float)hf);
  h = __builtin_bit_cast(u16, hf);
  l = __builtin_bit_cast(u16, lf);
}

// ---------------------------------------------------------------- precompute
__global__ void precompute_kernel(const float* __restrict__ Lre, const float* __restrict__ Lim,
                                  const float* __restrict__ lst,
                                  const float* __restrict__ Ere, const float* __restrict__ Eim,
                                  const float* __restrict__ Fre, const float* __restrict__ Fim,
                                  float* __restrict__ Lbr, float* __restrict__ Lbi,
                                  float* __restrict__ cfr, float* __restrict__ cfi,
                                  float* __restrict__ EFr, float* __restrict__ EFi)
{
  int p = blockIdx.x * blockDim.x + threadIdx.x;
  if (p >= PP) return;
  float lre = fminf(Lre[p], -1e-4f);   // clip_eigs
  float lim = Lim[p];
  float st  = expf(lst[p]);
  float er  = expf(lre * st);
  float s, c;
  sincosf(lim * st, &s, &c);
  float lbr = er * c, lbi = er * s;    // Lambda_bar
  Lbr[p] = lbr; Lbi[p] = lbi;
  float den = lre * lre + lim * lim;
  float nr  = lbr - 1.0f;
  cfr[p] = (nr * lre + lbi * lim) / den;
  cfi[p] = (lbi * lre - nr * lim) / den;
  for (int r = 0; r < RR; ++r) {
    float e_r = Ere[p * RR + r], e_i = Eim[p * RR + r];
    float f_r = Fre[r * PP + p], f_i = Fim[r * PP + p];
    EFr[r * PP + p] = e_r * f_r - e_i * f_i;
    EFi[r * PP + p] = e_r * f_i + e_i * f_r;
  }
}

// ---------------------------------------------------------------- B_bar -> single fp16 planes (re, im)
__global__ void bbar_kernel(const float* __restrict__ Bre, const float* __restrict__ Bim,
                            const float* __restrict__ cfr, const float* __restrict__ cfi,
                            u16* __restrict__ brp, u16* __restrict__ bip)
{
  int i = blockIdx.x * blockDim.x + threadIdx.x;
  int base = i * 4;
  if (base >= PP * HH) return;
  int p = base >> 10;
  float cr = cfr[p], ci = cfi[p];
  float4 br = *(const float4*)&Bre[base];
  float4 bi = *(const float4*)&Bim[base];
  ushort4 rp, ip;
  rp.x = h16(cr*br.x - ci*bi.x); ip.x = h16(cr*bi.x + ci*br.x);
  rp.y = h16(cr*br.y - ci*bi.y); ip.y = h16(cr*bi.y + ci*br.y);
  rp.z = h16(cr*br.z - ci*bi.z); ip.z = h16(cr*bi.z + ci*br.z);
  rp.w = h16(cr*br.w - ci*bi.w); ip.w = h16(cr*bi.w + ci*br.w);
  *(ushort4*)&brp[base] = rp;
  *(ushort4*)&bip[base] = ip;
}

// ---------------------------------------------------------------- u -> fp16 hi/lo (lo is normal-range: keep)
__global__ void split_u_kernel(const float* __restrict__ U,
                               u16* __restrict__ uh, u16* __restrict__ ul)
{
  int i = blockIdx.x * blockDim.x + threadIdx.x;
  int base = i * 4;
  float4 v = *(const float4*)&U[base];
  ushort4 h, l;
  splitf(v.x, h.x, l.x); splitf(v.y, h.y, l.y);
  splitf(v.z, h.z, l.z); splitf(v.w, h.w, l.w);
  *(ushort4*)&uh[base] = h;
  *(ushort4*)&ul[base] = l;
}

// ---------------------------------------------------------------- C -> single fp16 planes (Cim negated)
__global__ void convc_kernel(const float* __restrict__ Cre, const float* __restrict__ Cim,
                             u16* __restrict__ crp, u16* __restrict__ cip)
{
  int i = blockIdx.x * blockDim.x + threadIdx.x;
  int base = i * 4;
  float4 a = *(const float4*)&Cre[base];
  float4 b = *(const float4*)&Cim[base];
  ushort4 rp, ip;
  rp.x = h16(a.x); ip.x = h16(-b.x);
  rp.y = h16(a.y); ip.y = h16(-b.y);
  rp.z = h16(a.z); ip.z = h16(-b.z);
  rp.w = h16(a.w); ip.w = h16(-b.w);
  *(ushort4*)&crp[base] = rp;
  *(ushort4*)&cip[base] = ip;
}

// ---------------------------------------------------------------- Lambda elements (fp32)
__global__ __launch_bounds__(256) void lambda_kernel(
    const float* __restrict__ Dt, const float* __restrict__ EFr, const float* __restrict__ EFi,
    const float* __restrict__ Lbr, const float* __restrict__ Lbi,
    float* __restrict__ Ler, float* __restrict__ Lei)
{
  int gid = blockIdx.x * 256 + threadIdx.x;
  int l  = gid >> 7;
  int pq = (gid & 127) << 2;
  float4 ar = *(const float4*)&Lbr[pq];
  float4 ai = *(const float4*)&Lbi[pq];
#pragma unroll
  for (int r = 0; r < RR; ++r) {
    float d = Dt[l * RR + r];
    float4 er = *(const float4*)&EFr[r * PP + pq];
    float4 ei = *(const float4*)&EFi[r * PP + pq];
    ar.x = fmaf(d, er.x, ar.x); ar.y = fmaf(d, er.y, ar.y);
    ar.z = fmaf(d, er.z, ar.z); ar.w = fmaf(d, er.w, ar.w);
    ai.x = fmaf(d, ei.x, ai.x); ai.y = fmaf(d, ei.y, ai.y);
    ai.z = fmaf(d, ei.z, ai.z); ai.w = fmaf(d, ei.w, ai.w);
  }
  *(float4*)&Ler[(size_t)l * PP + pq] = ar;
  *(float4*)&Lei[(size_t)l * PP + pq] = ai;
}

// ---------------------------------------------------------------- gemm1: Bu = u @ B_bar^T
// A = u (hi/lo fp16), B = B_bar (re/im fp16). tile 128(L) x 64(P), 4 waves 2x2 (64x32).
// grid 256: p-panel = g&7 (XCD-resident B), l = g>>3.
__global__ __launch_bounds__(256, 2) void gemm1_mfma(
    const u16* __restrict__ uh, const u16* __restrict__ ul,
    const u16* __restrict__ brp, const u16* __restrict__ bip,
    float* __restrict__ Bur, float* __restrict__ Bui)
{
  __shared__ __align__(16) char smem[69632];
  u16* Alds = (u16*)smem;                  // [2][128][40]
  u16* Blds = (u16*)(smem + 40960);        // [2][64][40]
  float* Stg = (float*)smem;               // [2][128][68] epilogue

  int g = blockIdx.x;
  int p0 = (g & 7) * 64, l0 = (g >> 3) * 128;
  int t = threadIdx.x;
  int w = t >> 6, lane = t & 63;
  int wr = w >> 1, wc = w & 1;
  int rl = lane & 15, kg = lane >> 4;

  int cg = t & 3, pl = (t >> 2) & 1, rwb = t >> 3;   // rwb 0..31
  const u16* gA = pl ? ul : uh;
  const u16* gB = pl ? bip : brp;

  uint4 sA[4], sB[2];
  f32x4 accr[4][2], acci[4][2];
#pragma unroll
  for (int m = 0; m < 4; ++m)
#pragma unroll
    for (int n = 0; n < 2; ++n) {
      accr[m][n] = (f32x4){0.f,0.f,0.f,0.f};
      acci[m][n] = (f32x4){0.f,0.f,0.f,0.f};
    }

#define G1_LOADT(kt) do { int kc = (kt)*32 + cg*8;                              \
    _Pragma("unroll") for (int i2 = 0; i2 < 4; ++i2)                            \
      sA[i2] = *(const uint4*)&gA[(size_t)(l0 + rwb + 32*i2) * HH + kc];        \
    _Pragma("unroll") for (int i2 = 0; i2 < 2; ++i2)                            \
      sB[i2] = *(const uint4*)&gB[(size_t)(p0 + rwb + 32*i2) * HH + kc];        \
  } while (0)
#define G1_WRITET() do {                                                        \
    _Pragma("unroll") for (int i2 = 0; i2 < 4; ++i2)                            \
      *(uint4*)&Alds[pl*5120 + (rwb + 32*i2)*40 + cg*8] = sA[i2];               \
    _Pragma("unroll") for (int i2 = 0; i2 < 2; ++i2)                            \
      *(uint4*)&Blds[pl*2560 + (rwb + 32*i2)*40 + cg*8] = sB[i2];               \
  } while (0)

  G1_LOADT(0); G1_WRITET(); __syncthreads();
  for (int kt = 0; kt < HH/32; ++kt) {
    if (kt + 1 < HH/32) G1_LOADT(kt + 1);
    f16x8 fbr[2], fbi[2];
#pragma unroll
    for (int nf = 0; nf < 2; ++nf) {
      int brow = wc*32 + nf*16 + rl;
      fbr[nf] = *(const f16x8*)&Blds[brow*40 + kg*8];
      fbi[nf] = *(const f16x8*)&Blds[2560 + brow*40 + kg*8];
    }
#pragma unroll
    for (int mf = 0; mf < 4; ++mf) {
      int arow = wr*64 + mf*16 + rl;
      f16x8 fah = *(const f16x8*)&Alds[arow*40 + kg*8];
      f16x8 fal = *(const f16x8*)&Alds[5120 + arow*40 + kg*8];
#pragma unroll
      for (int nf = 0; nf < 2; ++nf) {
        accr[mf][nf] = MF16(fah, fbr[nf], accr[mf][nf]);
        accr[mf][nf] = MF16(fal, fbr[nf], accr[mf][nf]);
        acci[mf][nf] = MF16(fah, fbi[nf], acci[mf][nf]);
        acci[mf][nf] = MF16(fal, fbi[nf], acci[mf][nf]);
      }
    }
    __syncthreads();
    if (kt + 1 < HH/32) G1_WRITET();
    __syncthreads();
  }

  // epilogue: stage in LDS, write float4
#pragma unroll
  for (int mf = 0; mf < 4; ++mf)
#pragma unroll
    for (int nf = 0; nf < 2; ++nf)
#pragma unroll
      for (int j = 0; j < 4; ++j) {
        int r = wr*64 + mf*16 + kg*4 + j;
        int c = wc*32 + nf*16 + rl;
        Stg[r*68 + c]        = accr[mf][nf][j];
        Stg[8704 + r*68 + c] = acci[mf][nf][j];
      }
  __syncthreads();
  int col4 = (t & 15) * 4, rw2 = t >> 4;   // 16 rows/pass
#pragma unroll
  for (int i2 = 0; i2 < 8; ++i2) {
    int r = rw2 + 16*i2;
    float4 vr = *(const float4*)&Stg[r*68 + col4];
    float4 vi = *(const float4*)&Stg[8704 + r*68 + col4];
    *(float4*)&Bur[(size_t)(l0 + r) * PP + p0 + col4] = vr;
    *(float4*)&Bui[(size_t)(l0 + r) * PP + p0 + col4] = vi;
  }
}

// ---------------------------------------------------------------- scan phase 1
__global__ __launch_bounds__(256) void scan_agg_kernel(
    const float* __restrict__ Aer, const float* __restrict__ Aei,
    const float* __restrict__ Bur, const float* __restrict__ Bui,
    float* __restrict__ aggAr, float* __restrict__ aggAi,
    float* __restrict__ aggBr, float* __restrict__ aggBi)
{
  int tid = blockIdx.x * 256 + threadIdx.x;
  int p   = tid & (PP - 1);
  int c   = (tid >> 9) & (CH - 1);
  int dir = tid >> 16;
  float Ar = 1.f, Ai = 0.f, br = 0.f, bi = 0.f;
  int base = c * CL;
#pragma unroll
  for (int g = 0; g < CL / 8; ++g) {
    float ar8[8], ai8[8], br8[8], bi8[8];
#pragma unroll
    for (int u = 0; u < 8; ++u) {
      int l = base + g * 8 + u;
      int phys = dir ? (LL - 1 - l) : l;
      int idx = phys * PP + p;
      ar8[u] = Aer[idx]; ai8[u] = Aei[idx];
      br8[u] = Bur[idx]; bi8[u] = Bui[idx];
    }
#pragma unroll
    for (int u = 0; u < 8; ++u) {
      float nAr = ar8[u] * Ar - ai8[u] * Ai;
      float nAi = ar8[u] * Ai + ai8[u] * Ar;
      float nbr = fmaf(ar8[u], br, fmaf(-ai8[u], bi, br8[u]));
      float nbi = fmaf(ar8[u], bi, fmaf( ai8[u], br, bi8[u]));
      Ar = nAr; Ai = nAi; br = nbr; bi = nbi;
    }
  }
  aggAr[tid] = Ar; aggAi[tid] = Ai; aggBr[tid] = br; aggBi[tid] = bi;
}

// ---------------------------------------------------------------- scan phase 2
__global__ __launch_bounds__(256) void scan_carry_kernel(
    const float* __restrict__ aggAr, const float* __restrict__ aggAi,
    const float* __restrict__ aggBr, const float* __restrict__ aggBi,
    float* __restrict__ carR, float* __restrict__ carI)
{
  int tid = blockIdx.x * 256 + threadIdx.x;
  int p   = tid & (PP - 1);
  int dir = tid >> 9;
  float xr = 0.f, xi = 0.f;
  for (int c = 0; c < CH; ++c) {
    int idx = (dir * CH + c) * PP + p;
    carR[idx] = xr; carI[idx] = xi;
    float ar = aggAr[idx], ai = aggAi[idx];
    float br = aggBr[idx], bi = aggBi[idx];
    float nr = fmaf(ar, xr, fmaf(-ai, xi, br));
    float ni = fmaf(ar, xi, fmaf( ai, xr, bi));
    xr = nr; xi = ni;
  }
}

// ---------------------------------------------------------------- scan phase 3 (writes single fp16 planes)
__global__ __launch_bounds__(256) void scan_apply_kernel(
    const float* __restrict__ Aer, const float* __restrict__ Aei,
    const float* __restrict__ Bur, const float* __restrict__ Bui,
    const float* __restrict__ carR, const float* __restrict__ carI,
    u16* __restrict__ xrp, u16* __restrict__ xip)
{
  int tid = blockIdx.x * 256 + threadIdx.x;
  int p   = tid & (PP - 1);
  int c   = (tid >> 9) & (CH - 1);
  int dir = tid >> 16;
  float xr = carR[tid], xi = carI[tid];
  int base = c * CL;
  int cofs = dir * PP + p;      // column in merged [L][2P] planes
#pragma unroll
  for (int g = 0; g < CL / 8; ++g) {
    float ar8[8], ai8[8], br8[8], bi8[8];
#pragma unroll
    for (int u = 0; u < 8; ++u) {
      int l = base + g * 8 + u;
      int phys = dir ? (LL - 1 - l) : l;
      int idx = phys * PP + p;
      ar8[u] = Aer[idx]; ai8[u] = Aei[idx];
      br8[u] = Bur[idx]; bi8[u] = Bui[idx];
    }
#pragma unroll
    for (int u = 0; u < 8; ++u) {
      float nr = fmaf(ar8[u], xr, fmaf(-ai8[u], xi, br8[u]));
      float ni = fmaf(ar8[u], xi, fmaf( ai8[u], xr, bi8[u]));
      xr = nr; xi = ni;
      int l = base + g * 8 + u;
      int phys = dir ? (LL - 1 - l) : l;
      size_t col = (size_t)phys * (2 * PP) + cofs;
      xrp[col] = h16(xr);
      xip[col] = h16(xi);
    }
  }
}

// ---------------------------------------------------------------- gemm2: Y = 2*Re(xs @ C^T) + D*u
// A = xs (re/im fp16 [L][2P]), B = C (re, -im fp16 [H][2P]). tile 128x128, 4 waves 2x2 (64x64).
// grid 256: h-panel = g&7 (XCD-resident C), l = g>>3.
__global__ __launch_bounds__(256, 2) void gemm2_mfma(
    const u16* __restrict__ xrp, const u16* __restrict__ xip,
    const u16* __restrict__ crp, const u16* __restrict__ cip,
    const float* __restrict__ Dv, const float* __restrict__ U,
    float* __restrict__ Y)
{
  __shared__ __align__(16) char smem[67584];
  u16* Alds = (u16*)smem;                  // [2][128][40]
  u16* Blds = (u16*)(smem + 20480);        // [2][128][40]
  float* Stg = (float*)smem;               // [128][132] epilogue

  int g = blockIdx.x;
  int h0 = (g & 7) * 128, l0 = (g >> 3) * 128;
  int t = threadIdx.x;
  int w = t >> 6, lane = t & 63;
  int wr = w >> 1, wc = w & 1;
  int rl = lane & 15, kg = lane >> 4;

  int cg = t & 3, pl = (t >> 2) & 1, rwb = t >> 3;
  const u16* gA = pl ? xip : xrp;
  const u16* gB = pl ? cip : crp;

  uint4 sA[4], sB[4];
  f32x4 acc[4][4];
#pragma unroll
  for (int m = 0; m < 4; ++m)
#pragma unroll
    for (int n = 0; n < 4; ++n) acc[m][n] = (f32x4){0.f,0.f,0.f,0.f};

#define G2_LOADT(kt) do { int kc = (kt)*32 + cg*8;                              \
    _Pragma("unroll") for (int i2 = 0; i2 < 4; ++i2)                            \
      sA[i2] = *(const uint4*)&gA[(size_t)(l0 + rwb + 32*i2) * HH + kc];        \
    _Pragma("unroll") for (int i2 = 0; i2 < 4; ++i2)                            \
      sB[i2] = *(const uint4*)&gB[(size_t)(h0 + rwb + 32*i2) * HH + kc];        \
  } while (0)
#define G2_WRITET() do {                                                        \
    _Pragma("unroll") for (int i2 = 0; i2 < 4; ++i2)                            \
      *(uint4*)&Alds[pl*5120 + (rwb + 32*i2)*40 + cg*8] = sA[i2];               \
    _Pragma("unroll") for (int i2 = 0; i2 < 4; ++i2)                            \
      *(uint4*)&Blds[pl*5120 + (rwb + 32*i2)*40 + cg*8] = sB[i2];               \
  } while (0)

  G2_LOADT(0); G2_WRITET(); __syncthreads();
  for (int kt = 0; kt < HH/32; ++kt) {
    if (kt + 1 < HH/32) G2_LOADT(kt + 1);
    f16x8 fbr[4], fbi[4];
#pragma unroll
    for (int nf = 0; nf < 4; ++nf) {
      int brow = wc*64 + nf*16 + rl;
      fbr[nf] = *(const f16x8*)&Blds[brow*40 + kg*8];
      fbi[nf] = *(const f16x8*)&Blds[5120 + brow*40 + kg*8];
    }
#pragma unroll
    for (int mf = 0; mf < 4; ++mf) {
      int arow = wr*64 + mf*16 + rl;
      f16x8 far = *(const f16x8*)&Alds[arow*40 + kg*8];
      f16x8 fai = *(const f16x8*)&Alds[5120 + arow*40 + kg*8];
#pragma unroll
      for (int nf = 0; nf < 4; ++nf) {
        acc[mf][nf] = MF16(far, fbr[nf], acc[mf][nf]);
        acc[mf][nf] = MF16(fai, fbi[nf], acc[mf][nf]);
      }
    }
    __syncthreads();
    if (kt + 1 < HH/32) G2_WRITET();
    __syncthreads();
  }

  // epilogue: stage to LDS, fuse D*u, float4 stores
#pragma unroll
  for (int mf = 0; mf < 4; ++mf)
#pragma unroll
    for (int nf = 0; nf < 4; ++nf)
#pragma unroll
      for (int j = 0; j < 4; ++j) {
        int r = wr*64 + mf*16 + kg*4 + j;
        int c = wc*64 + nf*16 + rl;
        Stg[r*132 + c] = acc[mf][nf][j];
      }
  __syncthreads();
  int col4 = (t & 31) * 4, rw2 = t >> 5;   // 8 rows/pass
  float4 dv = *(const float4*)&Dv[h0 + col4];
#pragma unroll
  for (int i2 = 0; i2 < 16; ++i2) {
    int r = rw2 + 8*i2;
    float4 v  = *(const float4*)&Stg[r*132 + col4];
    float4 uu = *(const float4*)&U[(size_t)(l0 + r) * HH + h0 + col4];
    float4 o;
    o.x = 2.0f*v.x + dv.x*uu.x; o.y = 2.0f*v.y + dv.y*uu.y;
    o.z = 2.0f*v.z + dv.z*uu.z; o.w = 2.0f*v.w + dv.w*uu.w;
    *(float4*)&Y[(size_t)(l0 + r) * HH + h0 + col4] = o;
  }
}

// ---------------------------------------------------------------- launch
extern "C" void kernel_launch(void* const* d_in, const int* in_sizes, int n_in,
                              void* d_out, int out_size, void* d_ws, size_t ws_size,
                              hipStream_t stream)
{
  const float* U   = (const float*)d_in[0];
  const float* Lre = (const float*)d_in[1];
  const float* Lim = (const float*)d_in[2];
  const float* Bre = (const float*)d_in[3];
  const float* Bim = (const float*)d_in[4];
  const float* Cre = (const float*)d_in[5];
  const float* Cim = (const float*)d_in[6];
  const float* Ere = (const float*)d_in[7];
  const float* Eim = (const float*)d_in[8];
  const float* Fre = (const float*)d_in[9];
  const float* Fim = (const float*)d_in[10];
  const float* Dv  = (const float*)d_in[11];
  const float* lst = (const float*)d_in[12];
  const float* Dt  = (const float*)d_in[13];
  float* Y = (float*)d_out;

  char* wsb = (char*)d_ws;
  size_t o = 0;
  auto alloc = [&](size_t bytes) -> char* {
    char* r = wsb + o; o += (bytes + 255) & ~(size_t)255; return r;
  };
  float* Lbr = (float*)alloc(PP * 4);
  float* Lbi = (float*)alloc(PP * 4);
  float* cfr = (float*)alloc(PP * 4);
  float* cfi = (float*)alloc(PP * 4);
  float* EFr = (float*)alloc((size_t)RR * PP * 4);
  float* EFi = (float*)alloc((size_t)RR * PP * 4);
  u16* uh  = (u16*)alloc((size_t)LL * HH * 2);
  u16* ul  = (u16*)alloc((size_t)LL * HH * 2);
  u16* brp = (u16*)alloc((size_t)PP * HH * 2);
  u16* bip = (u16*)alloc((size_t)PP * HH * 2);
  float* Ler = (float*)alloc((size_t)LL * PP * 4);
  float* Lei = (float*)alloc((size_t)LL * PP * 4);
  float* Bur = (float*)alloc((size_t)LL * PP * 4);
  float* Bui = (float*)alloc((size_t)LL * PP * 4);
  u16* xrp = (u16*)alloc((size_t)LL * 2 * PP * 2);
  u16* xip = (u16*)alloc((size_t)LL * 2 * PP * 2);
  u16* crp = (u16*)alloc((size_t)HH * 2 * PP * 2);
  u16* cip = (u16*)alloc((size_t)HH * 2 * PP * 2);
  const int NAGG = 2 * CH * PP;       // 131072
  float* aggAr = (float*)alloc((size_t)NAGG * 4);
  float* aggAi = (float*)alloc((size_t)NAGG * 4);
  float* aggBr = (float*)alloc((size_t)NAGG * 4);
  float* aggBi = (float*)alloc((size_t)NAGG * 4);
  float* carR  = (float*)alloc((size_t)NAGG * 4);
  float* carI  = (float*)alloc((size_t)NAGG * 4);

  precompute_kernel<<<2, 256, 0, stream>>>(Lre, Lim, lst, Ere, Eim, Fre, Fim,
                                           Lbr, Lbi, cfr, cfi, EFr, EFi);
  bbar_kernel<<<PP * HH / 4 / 256, 256, 0, stream>>>(Bre, Bim, cfr, cfi, brp, bip);
  split_u_kernel<<<LL * HH / 4 / 256, 256, 0, stream>>>(U, uh, ul);
  lambda_kernel<<<LL * PP / 4 / 256, 256, 0, stream>>>(Dt, EFr, EFi, Lbr, Lbi, Ler, Lei);
  convc_kernel<<<HH * 2 * PP / 4 / 256, 256, 0, stream>>>(Cre, Cim, crp, cip);
  gemm1_mfma<<<256, 256, 0, stream>>>(uh, ul, brp, bip, Bur, Bui);
  scan_agg_kernel<<<2 * CH * PP / 256, 256, 0, stream>>>(Ler, Lei, Bur, Bui,
                                                         aggAr, aggAi, aggBr, aggBi);
  scan_carry_kernel<<<4, 256, 0, stream>>>(aggAr, aggAi, aggBr, aggBi, carR, carI);
  scan_apply_kernel<<<2 * CH * PP / 256, 256, 0, stream>>>(Ler, Lei, Bur, Bui, carR, carI,
                                                           xrp, xip);
  gemm2_mfma<<<256, 256, 0, stream>>>(xrp, xip, crp, cip, Dv, U, Y);
}